// Round 1
// baseline (757.237 us; speedup 1.0000x reference)
//
#include <hip/hip_runtime.h>
#include <math.h>

// dims
#define Bv 2
#define Cv 64
#define Hv 512
#define Wv 512
#define Tv 16
#define Kv 1024
#define KMAXv 256
#define HIDv 128
#define HWv (Hv * Wv) // 262144

// output flat offsets (f32 elements)
#define OFF_HEAVY 0
#define OFF_DETAIL 33554432
#define OFF_ALPHA 67108864
#define OFF_PROB 67633152
#define OFF_GATES 67635200
#define OFF_EC 67637248
#define OFF_BL 67637249

// ws layout (bytes): selflag int[2048] @0 ; cost float[2] @8192
#define WS_SEL_OFF 0
#define WS_COST_OFF 8192

// ---------------- selection + probabilities/gates + cost partials ----------------
__global__ __launch_bounds__(1024) void sel_kernel(const float* __restrict__ u,
                                                   float* __restrict__ out,
                                                   int* __restrict__ selflag,
                                                   float* __restrict__ costp) {
    int b = blockIdx.x;
    int t = threadIdx.x;
    __shared__ float us[Kv];
    __shared__ float red[16];

    float ui = u[b * Kv + t];
    us[t] = ui;
    __syncthreads();

    float p = 1.0f / (1.0f + __expf(-ui));
    float hard = (ui >= 0.0f) ? 1.0f : 0.0f;
    out[OFF_PROB + b * Kv + t] = p;
    out[OFF_GATES + b * Kv + t] = (hard + p) - p; // STE forward

    float cost = p + (1.0f - p) * 0.1f;
    #pragma unroll
    for (int o = 32; o > 0; o >>= 1) cost += __shfl_down(cost, o, 64);
    int wave = t >> 6, lane = t & 63;
    if (lane == 0) red[wave] = cost;
    __syncthreads();
    if (t == 0) {
        float s = 0.f;
        #pragma unroll
        for (int i = 0; i < 16; i++) s += red[i];
        costp[b] = s;
    }

    // rank among masked values
    int selected = 0;
    if (ui >= 0.0f) {
        int r = 0;
        for (int j = 0; j < Kv; j += 4) {
            float4 uj = *(const float4*)&us[j];
            r += (uj.x > ui) || (uj.x == ui && (j + 0) < t);
            r += (uj.y > ui) || (uj.y == ui && (j + 1) < t);
            r += (uj.z > ui) || (uj.z == ui && (j + 2) < t);
            r += (uj.w > ui) || (uj.w == ui && (j + 3) < t);
        }
        selected = (r < KMAXv) ? 1 : 0;
    }
    selflag[b * Kv + t] = selected;
}

// ---------------- copy kernel: unselected tiles only, low-VGPR, BW-bound ----------------
__global__ __launch_bounds__(256) void copy_kernel(const float* __restrict__ x,
                                                   float* __restrict__ out,
                                                   const int* __restrict__ selflag,
                                                   const float* __restrict__ costp) {
    int blk = blockIdx.x;
    int t = threadIdx.x;

    if (blk == 0 && t == 0) {
        float ec = costp[0] + costp[1];
        out[OFF_EC] = ec;
        out[OFF_BL] = (ec > 1024.0f) ? (ec - 1024.0f) : 0.0f;
    }

    if (selflag[blk]) return;

    int b = blk >> 10;
    int tile = blk & 1023;
    int gh = tile >> 5, gw = tile & 31;
    int h0 = gh * Tv, w0 = gw * Tv;

    int cplane = t >> 6;         // 0..3
    int r = (t >> 2) & 15;       // row in tile
    int q = t & 3;               // float4 within row
    int base = ((b * Cv + cplane) * Hv + (h0 + r)) * Wv + w0 + q * 4;
    float4 z = make_float4(0.f, 0.f, 0.f, 0.f);
    #pragma unroll 4
    for (int c4 = 0; c4 < 16; c4++) {
        int idx = base + c4 * 4 * HWv;
        float4 v = *(const float4*)&x[idx];
        *(float4*)&out[OFF_HEAVY + idx] = v;
        *(float4*)&out[OFF_DETAIL + idx] = z;
    }
    if (t < 64) {
        int r2 = t >> 2, q2 = t & 3;
        int aidx = (b * Hv + h0 + r2) * Wv + w0 + q2 * 4;
        *(float4*)&out[OFF_ALPHA + aidx] = z;
    }
}

// ---------------- mlp kernel: selected tiles, hid-chunked, LDS-staged x ----------------
// launch_bounds(256, 2): LDS (64.5 KB) caps at 2 blocks/CU and there are only
// 512 working blocks (= 8 waves/CU) anyway, so let the allocator use up to
// 256 VGPR/thread. D[64]+Hc[32] MUST live in registers: every index into
// these arrays below is compile-time (full unrolls) — rule #20.
__global__ __launch_bounds__(256, 2) void mlp_kernel(const float* __restrict__ x,
                                                     const float* __restrict__ W1,
                                                     const float* __restrict__ b1,
                                                     const float* __restrict__ W2,
                                                     const float* __restrict__ b2,
                                                     const float* __restrict__ Wa,
                                                     const float* __restrict__ ba,
                                                     float* __restrict__ out,
                                                     const int* __restrict__ selflag) {
    int blk = blockIdx.x;
    if (!selflag[blk]) return;

    __shared__ float xs[Cv][257]; // stride 257: (c + p) % 32 bank -> 2-way, free
    int t = threadIdx.x;
    int b = blk >> 10;
    int tile = blk & 1023;
    int gh = tile >> 5, gw = tile & 31;
    int h0 = gh * Tv, w0 = gw * Tv;

    int pr = t >> 4, pc = t & 15;
    int pbase = ((b * Cv) * Hv + (h0 + pr)) * Wv + w0 + pc; // channel-0 addr of my pixel

    // stage x tile into LDS: xs[c][pixel]
    #pragma unroll 8
    for (int c = 0; c < Cv; c++) xs[c][t] = x[pbase + c * HWv];
    __syncthreads();

    // alpha = sigmoid(x . Wa + ba)
    float aacc = ba[0];
    #pragma unroll 8
    for (int c = 0; c < Cv; c++) aacc += xs[c][t] * Wa[c];
    float alpha = 1.0f / (1.0f + __expf(-aacc));
    out[OFF_ALPHA + (b * Hv + h0 + pr) * Wv + w0 + pc] = alpha;

    // detail accumulators, init to b2  (compile-time indices only!)
    float D[Cv];
    #pragma unroll
    for (int c4 = 0; c4 < 16; c4++) {
        float4 bb = *(const float4*)&b2[c4 * 4];
        D[4 * c4 + 0] = bb.x; D[4 * c4 + 1] = bb.y;
        D[4 * c4 + 2] = bb.z; D[4 * c4 + 3] = bb.w;
    }

    // hid-chunked two-layer MLP
    for (int d0 = 0; d0 < HIDv; d0 += 32) {
        float Hc[32];
        #pragma unroll
        for (int j4 = 0; j4 < 8; j4++) {
            float4 bb = *(const float4*)&b1[d0 + 4 * j4];
            Hc[4 * j4 + 0] = bb.x; Hc[4 * j4 + 1] = bb.y;
            Hc[4 * j4 + 2] = bb.z; Hc[4 * j4 + 3] = bb.w;
        }
        // layer 1: Hc[j] += x_c * W1[c][d0+j]  (weights wave-uniform -> scalar loads)
        #pragma unroll 2
        for (int c = 0; c < Cv; c++) {
            float xc = xs[c][t];
            const float4* w1p = (const float4*)(W1 + c * HIDv + d0);
            #pragma unroll
            for (int j4 = 0; j4 < 8; j4++) {
                float4 w = w1p[j4];
                Hc[4 * j4 + 0] += xc * w.x;
                Hc[4 * j4 + 1] += xc * w.y;
                Hc[4 * j4 + 2] += xc * w.z;
                Hc[4 * j4 + 3] += xc * w.w;
            }
        }
        // gelu (tanh approx, matches jax.nn.gelu)
        #pragma unroll
        for (int j = 0; j < 32; j++) {
            float zv = Hc[j];
            float zz = 0.7978845608028654f * (zv + 0.044715f * zv * zv * zv);
            float e = __expf(2.0f * zz);
            float th = 1.0f - 2.0f / (e + 1.0f);
            Hc[j] = 0.5f * zv * (1.0f + th);
        }
        // layer 2: D[c] += Hc[j] * W2[d0+j][c]  — j loop FULLY unrolled so Hc[j]
        // is a compile-time index (partial unroll put Hc+D in scratch: VGPR=88,
        // ~75 MB scratch HBM traffic, VALUBusy 16%)
        #pragma unroll
        for (int j = 0; j < 32; j++) {
            float hj = Hc[j];
            const float4* w2p = (const float4*)(W2 + (d0 + j) * Cv);
            #pragma unroll
            for (int c4 = 0; c4 < 16; c4++) {
                float4 w = w2p[c4];
                D[4 * c4 + 0] += hj * w.x;
                D[4 * c4 + 1] += hj * w.y;
                D[4 * c4 + 2] += hj * w.z;
                D[4 * c4 + 3] += hj * w.w;
            }
        }
    }

    // epilogue: detail_out, heavy — FULL unroll (D[c] must stay compile-time)
    #pragma unroll
    for (int c = 0; c < Cv; c++) {
        int idx = pbase + c * HWv;
        float det = D[c];
        out[OFF_DETAIL + idx] = det;
        out[OFF_HEAVY + idx] = xs[c][t] + alpha * det;
    }
}

extern "C" void kernel_launch(void* const* d_in, const int* in_sizes, int n_in,
                              void* d_out, int out_size, void* d_ws, size_t ws_size,
                              hipStream_t stream) {
    const float* x  = (const float*)d_in[0];
    const float* u  = (const float*)d_in[1];
    const float* W1 = (const float*)d_in[2];
    const float* b1 = (const float*)d_in[3];
    const float* W2 = (const float*)d_in[4];
    const float* b2 = (const float*)d_in[5];
    const float* Wa = (const float*)d_in[6];
    const float* ba = (const float*)d_in[7];
    float* out = (float*)d_out;

    char* ws = (char*)d_ws;
    int*   selflag = (int*)(ws + WS_SEL_OFF);
    float* costp   = (float*)(ws + WS_COST_OFF);

    sel_kernel<<<Bv, 1024, 0, stream>>>(u, out, selflag, costp);
    copy_kernel<<<Bv * Kv, 256, 0, stream>>>(x, out, selflag, costp);
    mlp_kernel<<<Bv * Kv, 256, 0, stream>>>(x, W1, b1, W2, b2, Wa, ba, out, selflag);
}

// Round 2
// 748.039 us; speedup vs baseline: 1.0123x; 1.0123x over previous
//
#include <hip/hip_runtime.h>
#include <math.h>

// dims
#define Bv 2
#define Cv 64
#define Hv 512
#define Wv 512
#define Tv 16
#define Kv 1024
#define KMAXv 256
#define HIDv 128
#define HWv (Hv * Wv) // 262144

// output flat offsets (f32 elements)
#define OFF_HEAVY 0
#define OFF_DETAIL 33554432
#define OFF_ALPHA 67108864
#define OFF_PROB 67633152
#define OFF_GATES 67635200
#define OFF_EC 67637248
#define OFF_BL 67637249

// ws layout (bytes): selflag int[2048] @0 ; cost float[2] @8192
#define WS_SEL_OFF 0
#define WS_COST_OFF 8192

typedef float f4 __attribute__((ext_vector_type(4)));

// ---------------- selection + probabilities/gates + cost partials ----------------
__global__ __launch_bounds__(1024) void sel_kernel(const float* __restrict__ u,
                                                   float* __restrict__ out,
                                                   int* __restrict__ selflag,
                                                   float* __restrict__ costp) {
    int b = blockIdx.x;
    int t = threadIdx.x;
    __shared__ float us[Kv];
    __shared__ float red[16];

    float ui = u[b * Kv + t];
    us[t] = ui;
    __syncthreads();

    float p = 1.0f / (1.0f + __expf(-ui));
    float hard = (ui >= 0.0f) ? 1.0f : 0.0f;
    out[OFF_PROB + b * Kv + t] = p;
    out[OFF_GATES + b * Kv + t] = (hard + p) - p; // STE forward

    float cost = p + (1.0f - p) * 0.1f;
    #pragma unroll
    for (int o = 32; o > 0; o >>= 1) cost += __shfl_down(cost, o, 64);
    int wave = t >> 6, lane = t & 63;
    if (lane == 0) red[wave] = cost;
    __syncthreads();
    if (t == 0) {
        float s = 0.f;
        #pragma unroll
        for (int i = 0; i < 16; i++) s += red[i];
        costp[b] = s;
    }

    // rank among masked values
    int selected = 0;
    if (ui >= 0.0f) {
        int r = 0;
        for (int j = 0; j < Kv; j += 4) {
            float4 uj = *(const float4*)&us[j];
            r += (uj.x > ui) || (uj.x == ui && (j + 0) < t);
            r += (uj.y > ui) || (uj.y == ui && (j + 1) < t);
            r += (uj.z > ui) || (uj.z == ui && (j + 2) < t);
            r += (uj.w > ui) || (uj.w == ui && (j + 3) < t);
        }
        selected = (r < KMAXv) ? 1 : 0;
    }
    selflag[b * Kv + t] = selected;
}

// ---------------- copy kernel: unselected tiles only, low-VGPR, BW-bound ----------------
__global__ __launch_bounds__(256) void copy_kernel(const float* __restrict__ x,
                                                   float* __restrict__ out,
                                                   const int* __restrict__ selflag,
                                                   const float* __restrict__ costp) {
    int blk = blockIdx.x;
    int t = threadIdx.x;

    if (blk == 0 && t == 0) {
        float ec = costp[0] + costp[1];
        out[OFF_EC] = ec;
        out[OFF_BL] = (ec > 1024.0f) ? (ec - 1024.0f) : 0.0f;
    }

    if (selflag[blk]) return;

    int b = blk >> 10;
    int tile = blk & 1023;
    int gh = tile >> 5, gw = tile & 31;
    int h0 = gh * Tv, w0 = gw * Tv;

    int cplane = t >> 6;         // 0..3
    int r = (t >> 2) & 15;       // row in tile
    int q = t & 3;               // float4 within row
    int base = ((b * Cv + cplane) * Hv + (h0 + r)) * Wv + w0 + q * 4;
    float4 z = make_float4(0.f, 0.f, 0.f, 0.f);
    #pragma unroll 4
    for (int c4 = 0; c4 < 16; c4++) {
        int idx = base + c4 * 4 * HWv;
        float4 v = *(const float4*)&x[idx];
        *(float4*)&out[OFF_HEAVY + idx] = v;
        *(float4*)&out[OFF_DETAIL + idx] = z;
    }
    if (t < 64) {
        int r2 = t >> 2, q2 = t & 3;
        int aidx = (b * Hv + h0 + r2) * Wv + w0 + q2 * 4;
        *(float4*)&out[OFF_ALPHA + aidx] = z;
    }
}

// ---------------- mlp kernel ----------------
// Accumulators are NAMED ext_vector variables (D0..D15, H0..H7): first-class
// SSA values, so they CANNOT be demoted to scratch (rule #20 — `#pragma unroll`
// on float D[64] left the alloca in scratch: VGPR stayed 88, VALUBusy 16%).
// All component access is compile-time via macro expansion.

#define GELU1(ZV) { float zv_ = (ZV); \
    float zz_ = 0.7978845608028654f * (zv_ + 0.044715f * zv_ * zv_ * zv_); \
    float e_ = __expf(2.0f * zz_); \
    float th_ = 1.0f - 2.0f / (e_ + 1.0f); \
    (ZV) = 0.5f * zv_ * (1.0f + th_); }
#define GELU4(V) GELU1(V.x) GELU1(V.y) GELU1(V.z) GELU1(V.w)

// layer-2 scalar step: D += hj * W2row, advance row pointer
#define L2S(HJ) { float hj_ = (HJ); \
    D0  += hj_ * w2p[0];  D1  += hj_ * w2p[1];  D2  += hj_ * w2p[2];  D3  += hj_ * w2p[3]; \
    D4  += hj_ * w2p[4];  D5  += hj_ * w2p[5];  D6  += hj_ * w2p[6];  D7  += hj_ * w2p[7]; \
    D8  += hj_ * w2p[8];  D9  += hj_ * w2p[9];  D10 += hj_ * w2p[10]; D11 += hj_ * w2p[11]; \
    D12 += hj_ * w2p[12]; D13 += hj_ * w2p[13]; D14 += hj_ * w2p[14]; D15 += hj_ * w2p[15]; \
    w2p += 16; }
#define L2V(HV) L2S(HV.x) L2S(HV.y) L2S(HV.z) L2S(HV.w)

// epilogue per channel
#define EPI1(DC, C) { float det_ = (DC); int idx_ = pbase + (C) * HWv; \
    out[OFF_DETAIL + idx_] = det_; \
    out[OFF_HEAVY + idx_] = xs[C][t] + alpha * det_; }
#define EPI4(DV, C0) EPI1(DV.x, (C0)) EPI1(DV.y, (C0)+1) EPI1(DV.z, (C0)+2) EPI1(DV.w, (C0)+3)

__global__ __launch_bounds__(256, 2) void mlp_kernel(const float* __restrict__ x,
                                                     const float* __restrict__ W1,
                                                     const float* __restrict__ b1,
                                                     const float* __restrict__ W2,
                                                     const float* __restrict__ b2,
                                                     const float* __restrict__ Wa,
                                                     const float* __restrict__ ba,
                                                     float* __restrict__ out,
                                                     const int* __restrict__ selflag) {
    int blk = blockIdx.x;
    if (!selflag[blk]) return;

    __shared__ float xs[Cv][256]; // xs[c][pixel]; lanes read consecutive t -> conflict-free
    int t = threadIdx.x;
    int b = blk >> 10;
    int tile = blk & 1023;
    int gh = tile >> 5, gw = tile & 31;
    int h0 = gh * Tv, w0 = gw * Tv;

    int pr = t >> 4, pc = t & 15;
    int pbase = ((b * Cv) * Hv + (h0 + pr)) * Wv + w0 + pc; // channel-0 addr of my pixel

    // stage x tile into LDS: xs[c][pixel]
    #pragma unroll 8
    for (int c = 0; c < Cv; c++) xs[c][t] = x[pbase + c * HWv];
    __syncthreads();

    // alpha = sigmoid(x . Wa + ba)
    float aacc = ba[0];
    #pragma unroll 8
    for (int c = 0; c < Cv; c++) aacc += xs[c][t] * Wa[c];
    float alpha = 1.0f / (1.0f + __expf(-aacc));
    out[OFF_ALPHA + (b * Hv + h0 + pr) * Wv + w0 + pc] = alpha;

    // detail accumulators in named registers, init to b2
    f4 D0  = *(const f4*)&b2[0],  D1  = *(const f4*)&b2[4],  D2  = *(const f4*)&b2[8],  D3  = *(const f4*)&b2[12];
    f4 D4  = *(const f4*)&b2[16], D5  = *(const f4*)&b2[20], D6  = *(const f4*)&b2[24], D7  = *(const f4*)&b2[28];
    f4 D8  = *(const f4*)&b2[32], D9  = *(const f4*)&b2[36], D10 = *(const f4*)&b2[40], D11 = *(const f4*)&b2[44];
    f4 D12 = *(const f4*)&b2[48], D13 = *(const f4*)&b2[52], D14 = *(const f4*)&b2[56], D15 = *(const f4*)&b2[60];

    // hid-chunked two-layer MLP (4 chunks of 32 hid)
    #pragma unroll 1
    for (int d0 = 0; d0 < HIDv; d0 += 32) {
        f4 H0 = *(const f4*)&b1[d0 + 0],  H1 = *(const f4*)&b1[d0 + 4];
        f4 H2 = *(const f4*)&b1[d0 + 8],  H3 = *(const f4*)&b1[d0 + 12];
        f4 H4 = *(const f4*)&b1[d0 + 16], H5 = *(const f4*)&b1[d0 + 20];
        f4 H6 = *(const f4*)&b1[d0 + 24], H7 = *(const f4*)&b1[d0 + 28];

        // layer 1: H += x_c * W1[c][d0..d0+31]  (weights wave-uniform)
        #pragma unroll 4
        for (int c = 0; c < Cv; c++) {
            float xc = xs[c][t];
            const f4* w1p = (const f4*)(W1 + c * HIDv + d0);
            H0 += xc * w1p[0]; H1 += xc * w1p[1]; H2 += xc * w1p[2]; H3 += xc * w1p[3];
            H4 += xc * w1p[4]; H5 += xc * w1p[5]; H6 += xc * w1p[6]; H7 += xc * w1p[7];
        }

        // gelu (tanh approx, matches jax.nn.gelu)
        GELU4(H0) GELU4(H1) GELU4(H2) GELU4(H3)
        GELU4(H4) GELU4(H5) GELU4(H6) GELU4(H7)

        // layer 2: D += H_j * W2[d0+j][:]  (32 scalar steps, macro-unrolled)
        const f4* w2p = (const f4*)(W2 + d0 * Cv);
        L2V(H0) L2V(H1) L2V(H2) L2V(H3)
        L2V(H4) L2V(H5) L2V(H6) L2V(H7)
    }

    // epilogue: detail_out, heavy
    EPI4(D0, 0)   EPI4(D1, 4)   EPI4(D2, 8)   EPI4(D3, 12)
    EPI4(D4, 16)  EPI4(D5, 20)  EPI4(D6, 24)  EPI4(D7, 28)
    EPI4(D8, 32)  EPI4(D9, 36)  EPI4(D10, 40) EPI4(D11, 44)
    EPI4(D12, 48) EPI4(D13, 52) EPI4(D14, 56) EPI4(D15, 60)
}

extern "C" void kernel_launch(void* const* d_in, const int* in_sizes, int n_in,
                              void* d_out, int out_size, void* d_ws, size_t ws_size,
                              hipStream_t stream) {
    const float* x  = (const float*)d_in[0];
    const float* u  = (const float*)d_in[1];
    const float* W1 = (const float*)d_in[2];
    const float* b1 = (const float*)d_in[3];
    const float* W2 = (const float*)d_in[4];
    const float* b2 = (const float*)d_in[5];
    const float* Wa = (const float*)d_in[6];
    const float* ba = (const float*)d_in[7];
    float* out = (float*)d_out;

    char* ws = (char*)d_ws;
    int*   selflag = (int*)(ws + WS_SEL_OFF);
    float* costp   = (float*)(ws + WS_COST_OFF);

    sel_kernel<<<Bv, 1024, 0, stream>>>(u, out, selflag, costp);
    copy_kernel<<<Bv * Kv, 256, 0, stream>>>(x, out, selflag, costp);
    mlp_kernel<<<Bv * Kv, 256, 0, stream>>>(x, W1, b1, W2, b2, Wa, ba, out, selflag);
}